// Round 1
// baseline (394.661 us; speedup 1.0000x reference)
//
#include <hip/hip_runtime.h>
#include <math.h>

#define IMG_W 8192
#define PATCH 32
#define NPATCH 65536      // 256*256 patches
#define NBLK   256        // kernel A blocks: 1 block = 1 patch-row = 1 MiB contiguous

// ext_vector float4 so __builtin_nontemporal_load accepts it
typedef float f4 __attribute__((ext_vector_type(4)));

// ---------------------------------------------------------------------------
// Kernel A: fused patch-mean + loss terms.
//
// Layout change vs previous version: the old kernel gave each wave a
// 1 KiB-wide strip read with a 32 KiB row stride (8192 concurrent 1 KiB-
// granular streams) -> DRAM locality collapsed, effective BW ~1.7 TB/s.
// A patch-row (32 rows x 8192 cols) is 1 MiB CONTIGUOUS in memory, so:
//   block  = one patch-row ph   (256 blocks, 512 threads = 8 waves)
//   wave w = rows ph*32+4w .. +3 = 128 KiB fully contiguous stream
// Per lane, the column phase repeats every row: acc[j] (j=0..31) accumulates
// columns j*256 + lane*4 .. +3 across the wave's 4 rows. Patch sums are then
// an 8-lane shfl reduce (patch_local = 8*j + lane/8) + LDS combine across the
// 8 waves -> all 256 patches of the row are block-local.
//
// Non-temporal loads kept: the harness's 1 GiB 0xAA ws-fill right before
// this kernel leaves the 256 MiB LLC full of dirty lines; allocating reads
// would force ~256 MiB of writebacks inside our window.
//
// 16 loads (16 KiB per wave) kept in flight per batch: 8 waves/CU x 16 KiB
// = 128 KiB outstanding per CU >> the ~9 KiB needed to cover ~900cy HBM
// latency at 24.6 GB/s/CU, so occupancy=8 waves/CU still saturates BW.
// ---------------------------------------------------------------------------
__global__ __launch_bounds__(512, 2) void fused_patch_loss_kernel(
    const float* __restrict__ x, const float* __restrict__ tmask,
    float* __restrict__ p_pos, float* __restrict__ p_neg,
    float* __restrict__ p_cnt)
{
    const int wave = threadIdx.x >> 6;   // 0..7
    const int lane = threadIdx.x & 63;
    const int ph   = blockIdx.x;         // patch-row 0..255

    const float* base = x + (size_t)ph * (PATCH * IMG_W)
                          + (size_t)wave * (4 * IMG_W)
                          + (size_t)lane * 4;

    float acc[32];
#pragma unroll
    for (int j = 0; j < 32; ++j) acc[j] = 0.0f;

#pragma unroll
    for (int r = 0; r < 4; ++r) {
        const float* rb = base + (size_t)r * IMG_W;
#pragma unroll
        for (int half = 0; half < 2; ++half) {
            const float* hb = rb + half * (16 * 256);
            f4 v[16];
#pragma unroll
            for (int i = 0; i < 16; ++i)
                v[i] = __builtin_nontemporal_load(
                    reinterpret_cast<const f4*>(hb + i * 256));
#pragma unroll
            for (int i = 0; i < 16; ++i)
                acc[half * 16 + i] += (v[i].x + v[i].y) + (v[i].z + v[i].w);
        }
    }

    // per-wave: 8-lane sub-group reduce; leader (lane&7)==0 holds the
    // 4-row partial for patch_local = 8*j + (lane>>3)
    __shared__ float red[8][256];
#pragma unroll
    for (int j = 0; j < 32; ++j) {
        float s = acc[j];
        s += __shfl_down(s, 4, 64);
        s += __shfl_down(s, 2, 64);
        s += __shfl_down(s, 1, 64);
        if ((lane & 7) == 0) red[wave][j * 8 + (lane >> 3)] = s;
    }
    __syncthreads();

    // threads 0..255: one patch each -> full 32-row patch sum -> loss terms
    float pos = 0.0f, neg = 0.0f, cnt = 0.0f;
    if (threadIdx.x < 256) {
        const int t = threadIdx.x;
        float s = ((red[0][t] + red[1][t]) + (red[2][t] + red[3][t]))
                + ((red[4][t] + red[5][t]) + (red[6][t] + red[7][t]));
        const float m = s * (1.0f / 1024.0f);
        const float tm = tmask[ph * 256 + t];
        // logpdf = -0.5*z^2 - log(0.04*sqrt(2*pi)); log const = -2.2999373
        const float z = (m - 0.34f) * 25.0f;
        const float logpdf = -0.5f * z * z + 2.2999373f;
        const float pterm = -logf(expf(logpdf) + 1e-6f);
        if (tm >= 0.5f) { pos = pterm; cnt = 1.0f; }
        else            { neg = m * m; }
    }

    // block reduce 512 threads -> 3 scalars
    pos += __shfl_down(pos, 32, 64);
    neg += __shfl_down(neg, 32, 64);
    cnt += __shfl_down(cnt, 32, 64);
    pos += __shfl_down(pos, 16, 64);
    neg += __shfl_down(neg, 16, 64);
    cnt += __shfl_down(cnt, 16, 64);
    pos += __shfl_down(pos, 8, 64);
    neg += __shfl_down(neg, 8, 64);
    cnt += __shfl_down(cnt, 8, 64);
    pos += __shfl_down(pos, 4, 64);
    neg += __shfl_down(neg, 4, 64);
    cnt += __shfl_down(cnt, 4, 64);
    pos += __shfl_down(pos, 2, 64);
    neg += __shfl_down(neg, 2, 64);
    cnt += __shfl_down(cnt, 2, 64);
    pos += __shfl_down(pos, 1, 64);
    neg += __shfl_down(neg, 1, 64);
    cnt += __shfl_down(cnt, 1, 64);

    __shared__ float sp[8], sn[8], sc[8];
    if (lane == 0) { sp[wave] = pos; sn[wave] = neg; sc[wave] = cnt; }
    __syncthreads();

    if (threadIdx.x == 0) {
        float P = ((sp[0] + sp[1]) + (sp[2] + sp[3]))
                + ((sp[4] + sp[5]) + (sp[6] + sp[7]));
        float N = ((sn[0] + sn[1]) + (sn[2] + sn[3]))
                + ((sn[4] + sn[5]) + (sn[6] + sn[7]));
        float C = ((sc[0] + sc[1]) + (sc[2] + sc[3]))
                + ((sc[4] + sc[5]) + (sc[6] + sc[7]));
        p_pos[blockIdx.x] = P;
        p_neg[blockIdx.x] = N;
        p_cnt[blockIdx.x] = C;
    }
}

// ---------------------------------------------------------------------------
// Kernel B: single-block reduction of 256 partials x3 + finalize scalar.
// ---------------------------------------------------------------------------
__global__ __launch_bounds__(256) void finalize_reduce_kernel(
    const float* __restrict__ p_pos, const float* __restrict__ p_neg,
    const float* __restrict__ p_cnt, float* __restrict__ out)
{
    const int t = threadIdx.x;
    float pos = p_pos[t];
    float neg = p_neg[t];
    float cnt = p_cnt[t];

#pragma unroll
    for (int off = 32; off >= 1; off >>= 1) {
        pos += __shfl_down(pos, off, 64);
        neg += __shfl_down(neg, off, 64);
        cnt += __shfl_down(cnt, off, 64);
    }

    __shared__ float sp[4], sn[4], sc[4];
    const int wave = threadIdx.x >> 6;
    const int lane = threadIdx.x & 63;
    if (lane == 0) { sp[wave] = pos; sn[wave] = neg; sc[wave] = cnt; }
    __syncthreads();

    if (threadIdx.x == 0) {
        const float P = (sp[0] + sp[1]) + (sp[2] + sp[3]);
        const float N = (sn[0] + sn[1]) + (sn[2] + sn[3]);
        const float C = (sc[0] + sc[1]) + (sc[2] + sc[3]);
        out[0] = P / C + N / ((float)NPATCH - C);
    }
}

extern "C" void kernel_launch(void* const* d_in, const int* in_sizes, int n_in,
                              void* d_out, int out_size, void* d_ws, size_t ws_size,
                              hipStream_t stream)
{
    const float* unet  = (const float*)d_in[0];   // [1,1,8192,8192] fp32
    const float* trans = (const float*)d_in[1];   // [1,256,256] fp32
    float* out = (float*)d_out;                   // scalar fp32

    float* p_pos = (float*)d_ws;                  // [256]
    float* p_neg = p_pos + NBLK;                  // [256]
    float* p_cnt = p_neg + NBLK;                  // [256]

    fused_patch_loss_kernel<<<NBLK, 512, 0, stream>>>(unet, trans, p_pos, p_neg, p_cnt);
    finalize_reduce_kernel<<<1, 256, 0, stream>>>(p_pos, p_neg, p_cnt, out);
}

// Round 2
// 349.487 us; speedup vs baseline: 1.1293x; 1.1293x over previous
//
#include <hip/hip_runtime.h>
#include <math.h>

#define IMG_W   8192
#define NPATCH  65536     // 256*256 patches
#define NWAVES  8192      // kernel A: 2048 blocks x 4 waves
#define ABLK    2048
#define BBLK    256

// ext_vector float4 so __builtin_nontemporal_load accepts it
typedef float f4 __attribute__((ext_vector_type(4)));

// ---------------------------------------------------------------------------
// Kernel A: dense-sweep partial patch sums.
//
// DRAM-density theory (round-1 post-mortem): the harness fill hits 6.65 TB/s
// with a dense linear sweep; our round-0 (scattered 32 KiB windows) and
// round-1 (256 streams at 1 MiB power-of-2 stride) got 1.2-1.7 TB/s. So this
// version copies the fill's pattern: wave g reads 1 KiB chunks
// {g + 8192*i}, i=0..31 -> at any instant the 8192 resident waves cover a
// DENSE 8 MiB window sweeping the image linearly.
//
// Chunk c = 256 floats of one image row: row r = c>>5, seg = c&31.
// For wave g: seg = g&31 and rho = (g>>5)&31 (row-within-patch) are CONSTANT
// across i; patch-row ph = (g>>10) + 8*i. Per chunk, an 8-lane shfl reduce
// gives leader lanes (lane&7)==0 the sum over one patch-column's 32 columns
// for ONE image row. These single-row partials go to inter[rho][patch]
// (8 MiB, each element written exactly once -> deterministic, no atomics).
//
// Non-temporal loads kept: the 1 GiB ws fill right before us leaves the LLC
// full of dirty lines; nt reads avoid allocation -> no dirty writebacks.
// ---------------------------------------------------------------------------
__global__ __launch_bounds__(256) void patch_partial_kernel(
    const float* __restrict__ x, float* __restrict__ inter)
{
    const int wave = threadIdx.x >> 6;   // 0..3
    const int lane = threadIdx.x & 63;
    const int g    = blockIdx.x * 4 + wave;  // 0..8191
    const int seg  = g & 31;             // column segment within row
    const int rho  = (g >> 5) & 31;      // row within patch
    const int base = g >> 10;            // ph % 8

    const float* p0 = x + (size_t)g * 256 + (size_t)lane * 4;
    const int k = lane >> 3;             // leader's patch-col offset 0..7
    float* wout = inter + (size_t)rho * NPATCH + (size_t)seg * 8 + k;

#pragma unroll
    for (int b = 0; b < 4; ++b) {
        f4 v[8];
#pragma unroll
        for (int j = 0; j < 8; ++j) {
            const int i = b * 8 + j;
            v[j] = __builtin_nontemporal_load(
                reinterpret_cast<const f4*>(p0 + (size_t)i * (NWAVES * 256)));
        }
#pragma unroll
        for (int j = 0; j < 8; ++j) {
            float h = (v[j].x + v[j].y) + (v[j].z + v[j].w);
            h += __shfl_down(h, 4, 64);
            h += __shfl_down(h, 2, 64);
            h += __shfl_down(h, 1, 64);
            if ((lane & 7) == 0) {
                const int ph = base + 8 * (b * 8 + j);   // patch-row
                wout[(size_t)ph * 256] = h;
            }
        }
    }
}

// ---------------------------------------------------------------------------
// Kernel B: per-patch sum over the 32 rho-partials + loss terms + block
// partials. inter was written by the immediately-preceding kernel -> mostly
// L2/LLC-resident; reads are fully coalesced (consecutive threads ->
// consecutive patches).
// ---------------------------------------------------------------------------
__global__ __launch_bounds__(256) void patch_loss_kernel(
    const float* __restrict__ inter, const float* __restrict__ tmask,
    float* __restrict__ p_pos, float* __restrict__ p_neg,
    float* __restrict__ p_cnt)
{
    const int p = blockIdx.x * 256 + threadIdx.x;

    float s = 0.0f;
#pragma unroll
    for (int rho = 0; rho < 32; ++rho)
        s += inter[(size_t)rho * NPATCH + p];

    const float m = s * (1.0f / 1024.0f);
    const float tm = tmask[p];
    // logpdf = -0.5*z^2 - log(0.04*sqrt(2*pi)); log const = -2.2999373
    const float z = (m - 0.34f) * 25.0f;
    const float logpdf = -0.5f * z * z + 2.2999373f;
    const float pterm = -logf(expf(logpdf) + 1e-6f);

    float pos = 0.0f, neg = 0.0f, cnt = 0.0f;
    if (tm >= 0.5f) { pos = pterm; cnt = 1.0f; }
    else            { neg = m * m; }

    // block reduce 256 threads -> 3 scalars
#pragma unroll
    for (int off = 32; off >= 1; off >>= 1) {
        pos += __shfl_down(pos, off, 64);
        neg += __shfl_down(neg, off, 64);
        cnt += __shfl_down(cnt, off, 64);
    }

    __shared__ float sp[4], sn[4], sc[4];
    const int wave = threadIdx.x >> 6;
    const int lane = threadIdx.x & 63;
    if (lane == 0) { sp[wave] = pos; sn[wave] = neg; sc[wave] = cnt; }
    __syncthreads();

    if (threadIdx.x == 0) {
        p_pos[blockIdx.x] = (sp[0] + sp[1]) + (sp[2] + sp[3]);
        p_neg[blockIdx.x] = (sn[0] + sn[1]) + (sn[2] + sn[3]);
        p_cnt[blockIdx.x] = (sc[0] + sc[1]) + (sc[2] + sc[3]);
    }
}

// ---------------------------------------------------------------------------
// Kernel C: single-block reduction of 256 partials x3 + finalize scalar.
// ---------------------------------------------------------------------------
__global__ __launch_bounds__(256) void finalize_reduce_kernel(
    const float* __restrict__ p_pos, const float* __restrict__ p_neg,
    const float* __restrict__ p_cnt, float* __restrict__ out)
{
    const int t = threadIdx.x;
    float pos = p_pos[t];
    float neg = p_neg[t];
    float cnt = p_cnt[t];

#pragma unroll
    for (int off = 32; off >= 1; off >>= 1) {
        pos += __shfl_down(pos, off, 64);
        neg += __shfl_down(neg, off, 64);
        cnt += __shfl_down(cnt, off, 64);
    }

    __shared__ float sp[4], sn[4], sc[4];
    const int wave = threadIdx.x >> 6;
    const int lane = threadIdx.x & 63;
    if (lane == 0) { sp[wave] = pos; sn[wave] = neg; sc[wave] = cnt; }
    __syncthreads();

    if (threadIdx.x == 0) {
        const float P = (sp[0] + sp[1]) + (sp[2] + sp[3]);
        const float N = (sn[0] + sn[1]) + (sn[2] + sn[3]);
        const float C = (sc[0] + sc[1]) + (sc[2] + sc[3]);
        out[0] = P / C + N / ((float)NPATCH - C);
    }
}

extern "C" void kernel_launch(void* const* d_in, const int* in_sizes, int n_in,
                              void* d_out, int out_size, void* d_ws, size_t ws_size,
                              hipStream_t stream)
{
    const float* unet  = (const float*)d_in[0];   // [1,1,8192,8192] fp32
    const float* trans = (const float*)d_in[1];   // [1,256,256] fp32
    float* out = (float*)d_out;                   // scalar fp32

    float* inter = (float*)d_ws;                  // [32][65536] = 8 MiB
    float* p_pos = inter + 32 * NPATCH;           // [256]
    float* p_neg = p_pos + BBLK;                  // [256]
    float* p_cnt = p_neg + BBLK;                  // [256]

    patch_partial_kernel<<<ABLK, 256, 0, stream>>>(unet, inter);
    patch_loss_kernel<<<BBLK, 256, 0, stream>>>(inter, trans, p_pos, p_neg, p_cnt);
    finalize_reduce_kernel<<<1, 256, 0, stream>>>(p_pos, p_neg, p_cnt, out);
}